// Round 3
// baseline (881.272 us; speedup 1.0000x reference)
//
#include <hip/hip_runtime.h>

// Problem constants
#define H   512
#define W   512
#define C   256
#define KH  11
#define KW  11
#define OH  502
#define OW  502
#define OUT_MAP (OH * OW)   // 252004
#define HWSZ (H * W)

// Tiling: 256-wide x 32-tall output tile, 512 threads = 8 waves.
// Each wave owns 4 output rows; all 64 lanes of a wave read the SAME LDS row
// (stride-16B-per-lane => canonical conflict-free ds_read_b128 pattern).
#define TX 4                       // output px per lane, x
#define TY 4                       // output rows per wave
#define NWAVE 8
#define TILE_X 256                 // 64 lanes * TX
#define TILE_Y 32                  // 8 waves * TY
#define IN_ROWS (TILE_Y + KH - 1)  // 42
#define IN_XP   268                // LDS row stride (floats); 266 needed, %4==0 for b128
#define CPB     4                  // channels per block (z-split 64)
#define VEC_PER_ROW 67             // 67 float4 = 268 floats staged per row
#define NSTAGE_TOT (IN_ROWS * VEC_PER_ROW)   // 2814 float4 slots
#define NSTAGE_IT  6                         // ceil(2814/512)

__global__ __launch_bounds__(512, 6)   // 6 waves/EU -> 3 blocks/CU (LDS-capped anyway)
void conv_kernel(const float* __restrict__ x, const float* __restrict__ w,
                 float* __restrict__ out)
{
    __shared__ float s_in[IN_ROWS * IN_XP];   // 42*268*4 = 45024 B -> 3 blocks/CU

    const int tid  = threadIdx.x;
    const int lane = tid & 63;
    const int wv   = tid >> 6;       // wave id 0..7
    const int x0   = blockIdx.x * TILE_X;
    const int y0   = blockIdx.y * TILE_Y;
    const int c0   = blockIdx.z * CPB;

    // ---- channel-invariant staging descriptors (clamped, not zeroed:
    // garbage cells are only read by discarded out-of-range outputs) ----
    int s_goff[NSTAGE_IT];
    int s_loff[NSTAGE_IT];
    bool s_act[NSTAGE_IT];
#pragma unroll
    for (int j = 0; j < NSTAGE_IT; ++j) {
        int i = tid + j * 512;
        const bool act = (i < NSTAGE_TOT);
        if (!act) i = 0;
        const int row = i / VEC_PER_ROW;
        const int vec = i - row * VEC_PER_ROW;
        const int gy  = min(y0 + row, H - 1);
        const int gx  = min(x0 + vec * 4, W - 4);
        s_goff[j] = gy * W + gx;
        s_loff[j] = row * IN_XP + vec * 4;
        s_act[j]  = act;
    }

    float acc[TY][TX];
#pragma unroll
    for (int dy = 0; dy < TY; ++dy)
#pragma unroll
        for (int i = 0; i < TX; ++i) acc[dy][i] = 0.f;

    const int ry0 = wv * TY;         // wave's first output row within tile
    const int cx0 = lane * TX;       // lane's first output col within tile

    for (int cc = 0; cc < CPB; ++cc) {
        const int c = c0 + cc;
        const float* __restrict__ p0 = x + (size_t)c * HWSZ;       // batch 0
        const float* __restrict__ p1 = p0 + (size_t)C * HWSZ;      // batch 1

        // ---- stage batch-summed input tile into LDS ----
#pragma unroll
        for (int j = 0; j < NSTAGE_IT; ++j) {
            if (s_act[j]) {
                const float4 a = *(const float4*)(p0 + s_goff[j]);
                const float4 b = *(const float4*)(p1 + s_goff[j]);
                *(float4*)&s_in[s_loff[j]] =
                    make_float4(a.x + b.x, a.y + b.y, a.z + b.z, a.w + b.w);
            }
        }
        __syncthreads();

        // ---- compute: sliding-row window; whole wave reads one LDS row ----
        const float* __restrict__ wc = w + (size_t)c * (KH * KW);
#pragma unroll
        for (int r = 0; r < TY + KH - 1; ++r) {      // 14 input rows per wave
            const float* rp = &s_in[(ry0 + r) * IN_XP + cx0];
            const float4 a0 = *(const float4*)(rp + 0);
            const float4 a1 = *(const float4*)(rp + 4);
            const float4 a2 = *(const float4*)(rp + 8);
            const float4 a3 = *(const float4*)(rp + 12);
            const float win[16] = {a0.x, a0.y, a0.z, a0.w,
                                   a1.x, a1.y, a1.z, a1.w,
                                   a2.x, a2.y, a2.z, a2.w,
                                   a3.x, a3.y, a3.z, a3.w};
#pragma unroll
            for (int dy = 0; dy < TY; ++dy) {
                const int kh = r - dy;
                if (kh >= 0 && kh < KH) {
#pragma unroll
                    for (int kw = 0; kw < KW; ++kw) {
                        const float wv_ = wc[kh * KW + kw];   // uniform -> s_load
#pragma unroll
                        for (int i = 0; i < TX; ++i)
                            acc[dy][i] += win[kw + i] * wv_;
                    }
                }
            }
        }
        __syncthreads();
    }

    // ---- accumulate partials into bias-initialized output (batch 0 map) ----
#pragma unroll
    for (int dy = 0; dy < TY; ++dy) {
        const int oy = y0 + ry0 + dy;
        if (oy < OH) {
#pragma unroll
            for (int i = 0; i < TX; ++i) {
                const int ox = x0 + cx0 + i;
                if (ox < OW)
                    atomicAdd(&out[(size_t)oy * OW + ox], acc[dy][i]);
            }
        }
    }
}

__global__ void init_kernel(float* __restrict__ out, const float* __restrict__ bias)
{
    const int i = blockIdx.x * 256 + threadIdx.x;
    if (i < OUT_MAP) out[i] = bias[0];
}

__global__ void bcast_kernel(float* __restrict__ out)
{
    const int i = blockIdx.x * 256 + threadIdx.x;
    if (i < OUT_MAP) out[OUT_MAP + i] = out[i];
}

extern "C" void kernel_launch(void* const* d_in, const int* in_sizes, int n_in,
                              void* d_out, int out_size, void* d_ws, size_t ws_size,
                              hipStream_t stream)
{
    const float* x    = (const float*)d_in[0];   // (2,256,512,512) fp32
    const float* w    = (const float*)d_in[1];   // (1,256,11,11)  fp32
    const float* bias = (const float*)d_in[2];   // (1,)           fp32
    float* out = (float*)d_out;                  // (2,1,502,502)  fp32

    const int nb = (OUT_MAP + 255) / 256;
    init_kernel<<<nb, 256, 0, stream>>>(out, bias);
    conv_kernel<<<dim3(2, 16, 64), 512, 0, stream>>>(x, w, out);
    bcast_kernel<<<nb, 256, 0, stream>>>(out);
}